// Round 12
// baseline (414.418 us; speedup 1.0000x reference)
//
#include <hip/hip_runtime.h>
#include <utility>

// Problem constants
// DIM_IN=128, DIM_OUT=128, DIM_X=256, L=256, BATCH=8192, fp32 everywhere.
#define NB 8192

// ---------- static_for helper (compile-time register indices) ----------
template <typename F, size_t... I>
__device__ __forceinline__ void sfor_impl(F&& f, std::index_sequence<I...>) {
  (f(std::integral_constant<int, (int)I>{}), ...);
}
template <int N, typename F>
__device__ __forceinline__ void sfor(F&& f) {
  sfor_impl((F&&)f, std::make_index_sequence<N>{});
}

// packed-column-triangle offset: column li holds D[l2][li], l2=li+1..63, padded to x4
constexpr int coff(int li) {
  int o = 0;
  for (int j = 0; j < li; ++j) o += ((63 - j) + 3) & ~3;
  return o;
}
#define CPACK_STRIDE 2176  // > coff(63), float4-aligned

// fast reciprocal: v_rcp_f32 + one Newton step (~1 ulp). Avoids the ~10-instr
// IEEE divide sequence on serial critical paths (GJ pivot chain, tanh chain).
__device__ __forceinline__ float fast_rcp(float x) {
  float r = __builtin_amdgcn_rcpf(x);
  return r * (2.0f - x * r);
}

// fast tanh: 1 - 2/(exp(2x)+1). Clamp keeps e finite so the rcp Newton step
// can't see inf*0 = NaN; |x| is < ~35 in this problem anyway.
__device__ __forceinline__ float fast_tanh(float x) {
  const float e = __expf(2.0f * fminf(x, 40.0f));
  return 1.0f - 2.0f * fast_rcp(e + 1.0f);
}

// =================== device functions (fused into mega kernels) ===================

// ---------- prep: cx[l] = C1[l,:]·x ; xF[k] = Fm[k,:]·x ; rLam = 1/Lam ----------
__device__ void dev_prep(const float* __restrict__ x, const float* __restrict__ C1,
                         const float* __restrict__ Fm, const float* __restrict__ Lam,
                         float* __restrict__ cx, float* __restrict__ xF,
                         float* __restrict__ rLam, int t) {
  float s1 = 0.f, s2 = 0.f;
  for (int i = 0; i < 256; ++i) {
    const float xi = x[i];
    s1 += C1[t * 256 + i] * xi;
    s2 += Fm[t * 256 + i] * xi;
  }
  cx[t] = s1;
  xF[t] = s2;
  rLam[t] = 1.0f / Lam[t];
}

// ---------- pack D11 chunk-triangles column-major (256 active threads) ----------
__device__ void dev_pack(const float* __restrict__ D11, float* __restrict__ cpack,
                         int t) {
  const int c = t >> 6;
  const int lane = t & 63;
  int off = 0;
  for (int li = 0; li < 63; ++li) {
    if (lane < 63 - li)
      cpack[c * CPACK_STRIDE + off + lane] =
          D11[(c * 64 + li + 1 + lane) * 256 + (c * 64 + li)];
    off += ((63 - li) + 3) & ~3;
  }
}

// ---------- blocked-panel GJ inverse of 128x128, 512 threads, 8x4 register tiles --
// A[r][c] = srcT[c*ld + r]; output dstT[c*128 + r] with the SAME element mapping as
// the load -> the only cross-step state is the a-tile, so the 8 outer steps can be
// SPLIT ACROSS KERNELS via a 64 KB global spill (measured: took mega1 from 53us
// off the critical path; each half rides alongside a batch-work kernel).
__device__ void dev_inv(const float* __restrict__ srcT, int ld,
                        float* __restrict__ dstT, int tid, int s0, int s1) {
  __shared__ float Pcols[128][20];  // [r][kk] current panel columns (pad 20)
  __shared__ float MB[128][20];     // [r][kk] panel transform M (pad 20)
  __shared__ float Ar[16][132];     // [kk][c] OLD panel-row values (pad 132)
  __shared__ float invD[16 * 20];   // [kk][j] pivot-block inverse (pad 20)
  const int ti = tid >> 5;          // 0..15  -> R = 8*ti (8 rows)
  const int tj = tid & 31;          // 0..31  -> C = 4*tj (4 cols)
  const int R = ti * 8, C = tj * 4;
  float a[8][4];
#pragma unroll
  for (int j = 0; j < 4; ++j)
#pragma unroll
    for (int g = 0; g < 2; ++g) {
      const float4 v = *(const float4*)&srcT[(C + j) * ld + (R + 4 * g)];
      a[4 * g + 0][j] = v.x; a[4 * g + 1][j] = v.y;
      a[4 * g + 2][j] = v.z; a[4 * g + 3][j] = v.w;
    }

  for (int s = s0; s < s1; ++s) {
    // ---- stage panel columns (col-tile owners) + old panel rows (row-tile owners)
    if ((tj >> 2) == s) {
      const int c0 = C - 16 * s;  // 0,4,8,12
#pragma unroll
      for (int i = 0; i < 8; ++i)
        *(float4*)&Pcols[R + i][c0] =
            make_float4(a[i][0], a[i][1], a[i][2], a[i][3]);
    }
    if ((ti >> 1) == s) {
      const int r0 = R - 16 * s;  // 0 or 8
#pragma unroll
      for (int i = 0; i < 8; ++i)
        *(float4*)&Ar[r0 + i][C] =
            make_float4(a[i][0], a[i][1], a[i][2], a[i][3]);
    }
    __syncthreads();

    // ---- 1a: invert 16x16 pivot block, 16 lanes; readlane broadcast + fast rcp
    if (tid < 16) {
      float q[16];
#pragma unroll
      for (int g = 0; g < 4; ++g) {
        const float4 v = *(const float4*)&Pcols[s * 16 + tid][4 * g];
        q[4 * g] = v.x; q[4 * g + 1] = v.y; q[4 * g + 2] = v.z; q[4 * g + 3] = v.w;
      }
#pragma unroll
      for (int kk = 0; kk < 16; ++kk) {
        float ps[16];
#pragma unroll
        for (int j = 0; j < 16; ++j)
          ps[j] = __int_as_float(
              __builtin_amdgcn_readlane(__float_as_int(q[j]), kk));
        const float piv = fast_rcp(ps[kk]);
#pragma unroll
        for (int j = 0; j < 16; ++j) ps[j] = (j == kk) ? piv : ps[j] * piv;
        const bool isP = (tid == kk);
        const float te = isP ? -1.0f : q[kk];
#pragma unroll
        for (int j = 0; j < 16; ++j) {
          const float base = (isP || j == kk) ? 0.0f : q[j];
          q[j] = base - te * ps[j];
        }
      }
#pragma unroll
      for (int g = 0; g < 4; ++g)
        *(float4*)&invD[tid * 20 + 4 * g] =
            make_float4(q[4 * g], q[4 * g + 1], q[4 * g + 2], q[4 * g + 3]);
    }
    __syncthreads();

    // ---- 1b: M[r][0..15], thread (r = tid&127, h = tid>>7) does cols 4h..4h+3 ---
    {
      const int r = tid & 127, h = tid >> 7;  // h: 0..3
      float4 mv;
      if ((r >> 4) == s) {
        mv = *(const float4*)&invD[(r & 15) * 20 + 4 * h];
      } else {
        mv = make_float4(0.f, 0.f, 0.f, 0.f);
#pragma unroll
        for (int g = 0; g < 4; ++g) {
          const float4 p = *(const float4*)&Pcols[r][4 * g];
          const float pc[4] = {p.x, p.y, p.z, p.w};
#pragma unroll
          for (int q = 0; q < 4; ++q) {
            const float4 d = *(const float4*)&invD[(4 * g + q) * 20 + 4 * h];
            mv.x -= pc[q] * d.x; mv.y -= pc[q] * d.y;
            mv.z -= pc[q] * d.z; mv.w -= pc[q] * d.w;
          }
        }
      }
      *(float4*)&MB[r][4 * h] = mv;
    }
    __syncthreads();

    // ---- phase 2: register-tiled rank-16 update ----
    if ((tj >> 2) == s) {
      // panel columns replaced by M
      const int c0 = C - 16 * s;
#pragma unroll
      for (int i = 0; i < 8; ++i) {
        const float4 m = *(const float4*)&MB[R + i][c0];
        a[i][0] = m.x; a[i][1] = m.y; a[i][2] = m.z; a[i][3] = m.w;
      }
    } else {
      if ((ti >> 1) == s) {
#pragma unroll
        for (int i = 0; i < 8; ++i)
#pragma unroll
          for (int j = 0; j < 4; ++j) a[i][j] = 0.f;
      }
#pragma unroll
      for (int half = 0; half < 2; ++half) {
        float4 ar[8];
#pragma unroll
        for (int k = 0; k < 8; ++k)
          ar[k] = *(const float4*)&Ar[half * 8 + k][C];
#pragma unroll
        for (int i = 0; i < 8; ++i) {
          const float4 m0 = *(const float4*)&MB[R + i][half * 8];
          const float4 m1 = *(const float4*)&MB[R + i][half * 8 + 4];
          const float mi[8] = {m0.x, m0.y, m0.z, m0.w, m1.x, m1.y, m1.z, m1.w};
#pragma unroll
          for (int k = 0; k < 8; ++k) {
            a[i][0] += mi[k] * ar[k].x;
            a[i][1] += mi[k] * ar[k].y;
            a[i][2] += mi[k] * ar[k].z;
            a[i][3] += mi[k] * ar[k].w;
          }
        }
      }
    }
    __syncthreads();
  }
#pragma unroll
  for (int j = 0; j < 4; ++j)
#pragma unroll
    for (int g = 0; g < 2; ++g)
      *(float4*)&dstT[(C + j) * 128 + (R + 4 * g)] = make_float4(
          a[4 * g + 0][j], a[4 * g + 1][j], a[4 * g + 2][j], a[4 * g + 3][j]);
}

// ---------- transpose u (8192x128) into vw rows 256..383 (512-thread version) ----
__device__ void dev_T(const float* __restrict__ u, float* __restrict__ vw, int bid,
                      int t) {  // t in [0,512)
  __shared__ float buf[64 * 65];
  const int b0 = bid * 64;
#pragma unroll
  for (int h = 0; h < 2; ++h) {
#pragma unroll
    for (int q = 0; q < 8; ++q) {
      const int idx = q * 512 + t;
      const int bl = idx >> 6;
      const int i2 = idx & 63;
      buf[i2 * 65 + bl] = u[(b0 + bl) * 128 + 64 * h + i2];
    }
    __syncthreads();
#pragma unroll
    for (int q = 0; q < 8; ++q) {
      const int idx = q * 512 + t;
      const int i2 = idx >> 6;
      const int bl = idx & 63;
      vw[(256 + 64 * h + i2) * NB + b0 + bl] = buf[i2 * 65 + bl];
    }
    __syncthreads();
  }
}

// ---------- y-zero: 32 blocks x 512 threads clear y (8192x128) ----------
// Runs in mega1 (k_y now ACCUMULATES into y with fp32 atomics; ks=0 blocks seed
// y0, so the base must be zero before k_y; mega1 is kernels earlier -> no race).
__device__ void dev_yz(float* __restrict__ y, int role, int t) {
  float4* y4 = (float4*)y;
  const int idx0 = role * 512 + t;  // 16384 threads cover 262144 float4
  const float4 z = make_float4(0.f, 0.f, 0.f, 0.f);
#pragma unroll
  for (int q = 0; q < 16; ++q) y4[q * 16384 + idx0] = z;
}

// ---------- vw[l][b] = cx[l] + D12[l,:]·u[b,:] via u^T, 512 threads ----------
// 8 l-rows x 2048 b per block; 128 blocks (4 b-tiles x 32 l-groups).
__device__ void dev_du512(const float* __restrict__ D12, const float* __restrict__ cx,
                          float* __restrict__ vw, int bid, int t) {
  __shared__ float Dl[8 * 128];
  const int bx = bid & 3;
  const int l0 = (bid >> 2) * 8;
#pragma unroll
  for (int q = 0; q < 2; ++q) Dl[q * 512 + t] = D12[l0 * 128 + q * 512 + t];
  __syncthreads();
  const float4* vw4 = (const float4*)vw;
  float4* vw4o = (float4*)vw;
  const int b4 = bx * 512 + t;
  float4 acc[8];
#pragma unroll
  for (int j = 0; j < 8; ++j) {
    const float cj = cx[l0 + j];
    acc[j] = make_float4(cj, cj, cj, cj);
  }
#pragma unroll 4
  for (int i = 0; i < 128; ++i) {
    const float4 wv = vw4[(256 + i) * 2048 + b4];
#pragma unroll
    for (int j = 0; j < 8; ++j) {
      const float d = Dl[j * 128 + i];
      acc[j].x += d * wv.x;
      acc[j].y += d * wv.y;
      acc[j].z += d * wv.z;
      acc[j].w += d * wv.w;
    }
  }
#pragma unroll
  for (int j = 0; j < 8; ++j) vw4o[(l0 + j) * 2048 + b4] = acc[j];
}

// ---------- W = invA11 * A12 ; z1 = invA11 * c1 ----------
__device__ void dev_WZ(const float* __restrict__ E, const float* __restrict__ C2,
                       const float* __restrict__ inv1T, float* __restrict__ W,
                       float* __restrict__ z1, int gid) {
  const int half = gid >> 14;
  const int idx = gid & 16383;
  const int j = idx >> 7;   // wave-uniform
  const int i = idx & 127;  // lane
  float s = 0.f;
  if (half == 0) {
    for (int m = 0; m < 128; ++m) s += inv1T[m * 128 + i] * E[(128 + j) * 256 + m];
    W[i * 128 + j] = s;
  } else {
    for (int m = 0; m < 128; ++m) s += inv1T[m * 128 + i] * C2[j * 256 + m];
    z1[i * 128 + j] = s;
  }
}

// ---------- S^T = (A22 - A21 W)^T ; c2p = c2 - A21 z1 ----------
__device__ void dev_SC(const float* __restrict__ E, const float* __restrict__ C2,
                       const float* __restrict__ W, const float* __restrict__ z1,
                       float* __restrict__ STt, float* __restrict__ c2p, int gid) {
  if (gid < 16384) {
    const int jj = gid >> 7;
    const int i = gid & 127;
    float s = E[(128 + jj) * 256 + 128 + i];
    for (int m = 0; m < 128; ++m) s -= E[m * 256 + 128 + i] * W[m * 128 + jj];
    STt[jj * 128 + i] = s;
  } else {
    const int idx = gid - 16384;
    const int i = idx >> 7;
    const int o = idx & 127;
    float s = C2[o * 256 + 128 + i];
    for (int m = 0; m < 128; ++m) s -= E[m * 256 + 128 + i] * z1[m * 128 + o];
    c2p[i * 128 + o] = s;
  }
}

// ---------- g2 = invS * c2p ----------
__device__ void dev_G2(const float* __restrict__ inv2T, const float* __restrict__ c2p,
                       float* __restrict__ g2, int gid) {
  const int i = gid >> 7;
  const int o = gid & 127;
  float s = 0.f;
  for (int m = 0; m < 128; ++m) s += inv2T[m * 128 + i] * c2p[m * 128 + o];
  g2[i * 128 + o] = s;
}

// ---------- g1 = z1 - W * g2 ----------
__device__ void dev_G1(const float* __restrict__ W, const float* __restrict__ z1,
                       const float* __restrict__ g2, float* __restrict__ g1, int gid) {
  const int i = gid >> 7;
  const int o = gid & 127;
  float s = z1[i * 128 + o];
  for (int m = 0; m < 128; ++m) s -= W[i * 128 + m] * g2[m * 128 + o];
  g1[i * 128 + o] = s;
}

// ---------- R = [P | Q] (128 x 384) and y0 ----------
__device__ void dev_R(const float* __restrict__ B1, const float* __restrict__ B2,
                      const float* __restrict__ D21, const float* __restrict__ D22,
                      const float* __restrict__ g1, const float* __restrict__ g2,
                      const float* __restrict__ xF, float* __restrict__ R,
                      float* __restrict__ y0, int gid) {
  if (gid < 32768) {
    const int o = gid >> 8;
    const int l = gid & 255;
    float s = D21[o * 256 + l];
    for (int m = 0; m < 128; ++m) {
      s += g1[m * 128 + o] * B1[m * 256 + l];
      s += g2[m * 128 + o] * B1[(128 + m) * 256 + l];
    }
    R[o * 384 + l] = s;
  } else if (gid < 49152) {
    const int t2 = gid - 32768;
    const int o = t2 >> 7;
    const int i = t2 & 127;
    float s = D22[o * 128 + i];
    for (int m = 0; m < 128; ++m) {
      s += g1[m * 128 + o] * B2[m * 128 + i];
      s += g2[m * 128 + o] * B2[(128 + m) * 128 + i];
    }
    R[o * 384 + 256 + i] = s;
  } else if (gid < 49280) {
    const int o = gid - 49152;
    float s = 0.f;
    for (int m = 0; m < 128; ++m) {
      s += g1[m * 128 + o] * xF[m];
      s += g2[m * 128 + o] * xF[128 + m];
    }
    y0[o] = s;
  }
}

// ---------- right-looking 64-step scan chunk: v[64] in REGISTERS ----------
// MEASURED (R7): LDS-staging cpack+rLam (one coalesced pass, 512 threads) took
// the scan kernels out of the top-5 (-24us wall) -- the 64 serial steps were
// stalled on per-step global load latency at 1 wave/SIMD.
__device__ void dev_scan(const float* __restrict__ cpack,
                         const float* __restrict__ rLam, float* __restrict__ vw,
                         int c, int bid, int t) {
  __shared__ float sc[CPACK_STRIDE];  // 8704 B
  __shared__ float srl[64];
  for (int i = t; i < CPACK_STRIDE; i += 512) sc[i] = cpack[c * CPACK_STRIDE + i];
  if (t < 64) srl[t] = rLam[c * 64 + t];
  __syncthreads();
  if (t >= 256) return;

  const int b = bid * 256 + t;
  const int l0 = c * 64;
  const float4* cp4 = (const float4*)sc;
  float v[64];
#pragma unroll
  for (int li = 0; li < 64; ++li) v[li] = vw[(l0 + li) * NB + b];
  sfor<64>([&](auto LI) {
    constexpr int li = decltype(LI)::value;
    const float w = fast_tanh(v[li] * srl[li]);
    vw[(l0 + li) * NB + b] = w;  // fire-and-forget
    constexpr int n = 63 - li;
    constexpr int off4 = coff(li) / 4;
    sfor<(n + 3) / 4>([&](auto Q) {
      constexpr int q = decltype(Q)::value;
      const float4 d = cp4[off4 + q];
      if constexpr (4 * q + 0 < n) v[li + 1 + 4 * q + 0] += d.x * w;
      if constexpr (4 * q + 1 < n) v[li + 1 + 4 * q + 1] += d.y * w;
      if constexpr (4 * q + 2 < n) v[li + 1 + 4 * q + 2] += d.z * w;
      if constexpr (4 * q + 3 < n) v[li + 1 + 4 * q + 3] += d.w * w;
    });
  });
}

// ---------- cross-chunk rank-64 update (role = old 256-thread block id) ----------
__device__ void dev_upd(const float* __restrict__ D11, float* __restrict__ vw, int c,
                        int role, int lane) {
  float4* vw4 = (float4*)vw;
  const int b4 = (role & 7) * 256 + lane;
  const int lp0 = (c + 1) * 64 + (role >> 3) * 8;
  const int k0 = c * 64;
  float4 acc[8];
#pragma unroll
  for (int j = 0; j < 8; ++j) acc[j] = vw4[(lp0 + j) * 2048 + b4];
  for (int k = 0; k < 64; ++k) {
    const float4 wv = vw4[(k0 + k) * 2048 + b4];
#pragma unroll
    for (int j = 0; j < 8; ++j) {
      const float d = D11[(lp0 + j) * 256 + k0 + k];  // wave-uniform scalar
      acc[j].x += d * wv.x;
      acc[j].y += d * wv.y;
      acc[j].z += d * wv.z;
      acc[j].w += d * wv.w;
    }
  }
#pragma unroll
  for (int j = 0; j < 8; ++j) vw4[(lp0 + j) * 2048 + b4] = acc[j];
}

// =================== mega kernels (block-range dispatch) ===================
//   k1: T + prep + pack + inv1[0:4] + y-zero   k6: upd1 + inv2[4:8]
//   k2: du  + inv1[4:8]                        k7: scan2 + G2
//   k3: scan0 + WZ                             k8: upd2 + G1
//   k4: upd0 + SC                              k9: scan3 + R
//   k5: scan1 + inv2[0:4]                     k10: k_y (k-split 2, atomics)

__global__ __launch_bounds__(512) void mega1(const float* u, const float* x,
                                             const float* C1, const float* Fm,
                                             const float* Lam, const float* D11,
                                             const float* E, float* vw, float* cx,
                                             float* xF, float* rLam, float* cpack,
                                             float* invSt, float* y) {
  const int bid = blockIdx.x;
  const int t = threadIdx.x;
  if (bid < 128) {
    dev_T(u, vw, bid, t);  // all 512 threads participate (internal barriers)
  } else if (bid == 128) {
    if (t < 256) dev_prep(x, C1, Fm, Lam, cx, xF, rLam, t);  // no barriers inside
  } else if (bid == 129) {
    if (t < 256) dev_pack(D11, cpack, t);  // no barriers inside
  } else if (bid == 130) {
    dev_inv(E, 256, invSt, t, 0, 4);  // inv1 first half
  } else {
    dev_yz(y, bid - 131, t);  // bids 131..162: zero y for k_y atomics
  }
}

__global__ __launch_bounds__(512) void mega2(const float* D12, const float* cx,
                                             float* vw, const float* invSt,
                                             float* inv1T) {
  const int bid = blockIdx.x;
  const int t = threadIdx.x;
  if (bid < 128) dev_du512(D12, cx, vw, bid, t);
  else dev_inv(invSt, 128, inv1T, t, 4, 8);  // bid == 128: inv1 second half
}

__global__ __launch_bounds__(512) void mega3(const float* cpack, const float* rLam,
                                             float* vw, const float* E,
                                             const float* C2, const float* inv1T,
                                             float* W, float* z1) {
  const int bid = blockIdx.x;
  const int t = threadIdx.x;
  if (bid < 32) {
    dev_scan(cpack, rLam, vw, 0, bid, t);  // all 512 stage; t<256 run recurrence
  } else {
    dev_WZ(E, C2, inv1T, W, z1, (bid - 32) * 512 + t);  // 64 blocks
  }
}

__global__ __launch_bounds__(512) void mega4(const float* D11, float* vw,
                                             const float* E, const float* C2,
                                             const float* W, const float* z1,
                                             float* STt, float* c2p) {
  const int bid = blockIdx.x;
  const int t = threadIdx.x;
  if (bid < 96) dev_upd(D11, vw, 0, bid * 2 + (t >> 8), t & 255);  // roles 0..191
  else dev_SC(E, C2, W, z1, STt, c2p, (bid - 96) * 512 + t);       // 64 blocks
}

__global__ __launch_bounds__(512) void mega5(const float* cpack, const float* rLam,
                                             float* vw, const float* STt,
                                             float* inv2St) {
  const int bid = blockIdx.x;
  const int t = threadIdx.x;
  if (bid < 32) {
    dev_scan(cpack, rLam, vw, 1, bid, t);
  } else {
    dev_inv(STt, 128, inv2St, t, 0, 4);  // bid == 32: inv2 first half
  }
}

__global__ __launch_bounds__(512) void mega6(const float* D11, float* vw,
                                             const float* inv2St, float* inv2T) {
  const int bid = blockIdx.x;
  const int t = threadIdx.x;
  if (bid < 64) dev_upd(D11, vw, 1, bid * 2 + (t >> 8), t & 255);  // roles 0..127
  else dev_inv(inv2St, 128, inv2T, t, 4, 8);  // bid == 64: inv2 second half
}

__global__ __launch_bounds__(512) void mega7(const float* cpack, const float* rLam,
                                             float* vw, const float* inv2T,
                                             const float* c2p, float* g2) {
  const int bid = blockIdx.x;
  const int t = threadIdx.x;
  if (bid < 32) {
    dev_scan(cpack, rLam, vw, 2, bid, t);
  } else {
    dev_G2(inv2T, c2p, g2, (bid - 32) * 512 + t);  // 32 blocks
  }
}

__global__ __launch_bounds__(512) void mega8(const float* D11, float* vw,
                                             const float* W, const float* z1,
                                             const float* g2, float* g1) {
  const int bid = blockIdx.x;
  const int t = threadIdx.x;
  if (bid < 32) dev_upd(D11, vw, 2, bid * 2 + (t >> 8), t & 255);  // roles 0..63
  else dev_G1(W, z1, g2, g1, (bid - 32) * 512 + t);  // 32 blocks
}

__global__ __launch_bounds__(512) void mega9(const float* cpack, const float* rLam,
                                             float* vw, const float* B1,
                                             const float* B2, const float* D21,
                                             const float* D22, const float* g1,
                                             const float* g2, const float* xF,
                                             float* R, float* y0) {
  const int bid = blockIdx.x;
  const int t = threadIdx.x;
  if (bid < 32) {
    dev_scan(cpack, rLam, vw, 3, bid, t);
  } else {
    dev_R(B1, B2, D21, D22, g1, g2, xF, R, y0, (bid - 32) * 512 + t);  // 97 blk
  }
}

// ---------- y[b][o] += (ks==0 ? y0[o] : 0) + sum_{k in half} R[o][k] vw[k][b] ----
// v3 (measured A/B across R4/R6): 4x MLP change gave ~0 -> k_y is L3-BANDWIDTH
// bound (vw is cross-XCD -> L3-resident; ~800MB/47.7us ~= 17TB/s). Fix: o-tile 4
// halves L3 traffic to ~400MB; k-split 2 keeps 512 blocks (8 waves/CU) for
// latency hiding; fp32 atomicAdd combines the two k-half partials (y zeroed in
// mega1; ks=0 blocks seed y0). Atomic cost ~2M lane-FAAs ~= 1-2us.
__global__ __launch_bounds__(256) void k_y(const float* __restrict__ vw,
                                           const float* __restrict__ R,
                                           const float* __restrict__ y0,
                                           float* __restrict__ y) {
  __shared__ float Rl[768];  // [j][kk] 4 x 192 for this k-half
  const int tid = threadIdx.x;
  const int bid = blockIdx.x;      // 512 blocks
  const int gx = bid & 7;          // b-tile (XCD-aligned)
  const int gy = (bid >> 3) & 31;  // o-tile, 0..31
  const int ks = bid >> 8;         // k-half, 0..1
  const int o0 = gy * 4;
  const int kbase = ks * 192;
#pragma unroll
  for (int q = 0; q < 3; ++q) {
    const int e = q * 256 + tid;
    const int j = e / 192;
    const int kk = e - j * 192;
    Rl[e] = R[(o0 + j) * 384 + kbase + kk];
  }
  __syncthreads();

  const float4* vw4 = (const float4*)vw;
  const int b4 = gx * 256 + tid;
  float acc[4][4];
#pragma unroll
  for (int j = 0; j < 4; ++j) {
    const float init = (ks == 0) ? y0[o0 + j] : 0.f;
#pragma unroll
    for (int bi = 0; bi < 4; ++bi) acc[bi][j] = init;
  }
  for (int k = 0; k < 192; k += 8) {
    float4 w[8];
#pragma unroll
    for (int kk = 0; kk < 8; ++kk) w[kk] = vw4[(kbase + k + kk) * 2048 + b4];
#pragma unroll
    for (int j = 0; j < 4; ++j) {
      const float4 r0 = *(const float4*)&Rl[j * 192 + k];
      const float4 r1 = *(const float4*)&Rl[j * 192 + k + 4];
      acc[0][j] += r0.x * w[0].x + r0.y * w[1].x + r0.z * w[2].x + r0.w * w[3].x +
                   r1.x * w[4].x + r1.y * w[5].x + r1.z * w[6].x + r1.w * w[7].x;
      acc[1][j] += r0.x * w[0].y + r0.y * w[1].y + r0.z * w[2].y + r0.w * w[3].y +
                   r1.x * w[4].y + r1.y * w[5].y + r1.z * w[6].y + r1.w * w[7].y;
      acc[2][j] += r0.x * w[0].z + r0.y * w[1].z + r0.z * w[2].z + r0.w * w[3].z +
                   r1.x * w[4].z + r1.y * w[5].z + r1.z * w[6].z + r1.w * w[7].z;
      acc[3][j] += r0.x * w[0].w + r0.y * w[1].w + r0.z * w[2].w + r0.w * w[3].w +
                   r1.x * w[4].w + r1.y * w[5].w + r1.z * w[6].w + r1.w * w[7].w;
    }
  }
  const int b0 = b4 * 4;
#pragma unroll
  for (int bi = 0; bi < 4; ++bi)
#pragma unroll
    for (int j = 0; j < 4; ++j)
      atomicAdd(&y[(b0 + bi) * 128 + o0 + j], acc[bi][j]);
}

extern "C" void kernel_launch(void* const* d_in, const int* in_sizes, int n_in,
                              void* d_out, int out_size, void* d_ws, size_t ws_size,
                              hipStream_t stream) {
  const float* u   = (const float*)d_in[0];   // (8192,1,128)
  const float* x   = (const float*)d_in[1];   // (1,1,256)
  const float* Fm  = (const float*)d_in[2];   // (256,256)
  const float* B1  = (const float*)d_in[3];   // (256,256)
  const float* B2  = (const float*)d_in[4];   // (256,128)
  const float* C1  = (const float*)d_in[5];   // (256,256)
  const float* C2  = (const float*)d_in[6];   // (128,256)
  const float* D11 = (const float*)d_in[7];   // (256,256) strictly lower
  const float* D12 = (const float*)d_in[8];   // (256,128)
  const float* D21 = (const float*)d_in[9];   // (128,256)
  const float* D22 = (const float*)d_in[10];  // (128,128)
  const float* E   = (const float*)d_in[11];  // (256,256)
  const float* Lam = (const float*)d_in[12];  // (256,)
  float* y = (float*)d_out;                   // (8192,1,128) fp32

  float* F = (float*)d_ws;                     // ~13.4 MB used
  float* vw    = F;                            // 384*8192 (rows 256..383 = u^T)
  float* SMb   = F + 384 * NB;
  float* inv1T = SMb;                          // 16384
  float* Wm    = SMb + 16384;
  float* z1    = SMb + 32768;
  float* STt   = SMb + 49152;
  float* c2p   = SMb + 65536;
  float* inv2T = SMb + 81920;
  float* g2    = SMb + 98304;
  float* g1    = SMb + 114688;
  float* Rm    = SMb + 131072;                 // 128*384
  float* y0v   = SMb + 180224;                 // 128
  float* cx    = SMb + 180352;                 // 256
  float* xF    = SMb + 180608;                 // 256
  float* rLam  = SMb + 180864;                 // 256
  float* cpack = SMb + 181120;                 // 4*2176
  // inverse mid-state spills ALIAS dead regions (footprint unchanged):
  // invSt (inv1 state, live k1->k2) reuses STt (first written in k4);
  // inv2St (inv2 state, live k5->k6) reuses g1 (first written in k8).
  float* invSt  = STt;
  float* inv2St = g1;

  mega1<<<163, 512, 0, stream>>>(u, x, C1, Fm, Lam, D11, E, vw, cx, xF, rLam,
                                 cpack, invSt, y);
  mega2<<<129, 512, 0, stream>>>(D12, cx, vw, invSt, inv1T);
  mega3<<<96, 512, 0, stream>>>(cpack, rLam, vw, E, C2, inv1T, Wm, z1);
  mega4<<<160, 512, 0, stream>>>(D11, vw, E, C2, Wm, z1, STt, c2p);
  mega5<<<33, 512, 0, stream>>>(cpack, rLam, vw, STt, inv2St);
  mega6<<<65, 512, 0, stream>>>(D11, vw, inv2St, inv2T);
  mega7<<<64, 512, 0, stream>>>(cpack, rLam, vw, inv2T, c2p, g2);
  mega8<<<64, 512, 0, stream>>>(D11, vw, Wm, z1, g2, g1);
  mega9<<<129, 512, 0, stream>>>(cpack, rLam, vw, B1, B2, D21, D22, g1, g2, xF,
                                 Rm, y0v);
  k_y<<<512, 256, 0, stream>>>(vw, Rm, y0v, y);
}

// Round 17
// 320.964 us; speedup vs baseline: 1.2912x; 1.2912x over previous
//
#include <hip/hip_runtime.h>
#include <utility>

// Problem constants
// DIM_IN=128, DIM_OUT=128, DIM_X=256, L=256, BATCH=8192, fp32 everywhere.
#define NB 8192

// ---------- static_for helper (compile-time register indices) ----------
template <typename F, size_t... I>
__device__ __forceinline__ void sfor_impl(F&& f, std::index_sequence<I...>) {
  (f(std::integral_constant<int, (int)I>{}), ...);
}
template <int N, typename F>
__device__ __forceinline__ void sfor(F&& f) {
  sfor_impl((F&&)f, std::make_index_sequence<N>{});
}

// packed-column-triangle offset: column li holds D[l2][li], l2=li+1..63, padded to x4
constexpr int coff(int li) {
  int o = 0;
  for (int j = 0; j < li; ++j) o += ((63 - j) + 3) & ~3;
  return o;
}
#define CPACK_STRIDE 2176  // > coff(63), float4-aligned

// fast reciprocal: v_rcp_f32 + one Newton step (~1 ulp). Avoids the ~10-instr
// IEEE divide sequence on serial critical paths (GJ pivot chain, tanh chain).
__device__ __forceinline__ float fast_rcp(float x) {
  float r = __builtin_amdgcn_rcpf(x);
  return r * (2.0f - x * r);
}

// fast tanh: 1 - 2/(exp(2x)+1). Clamp keeps e finite so the rcp Newton step
// can't see inf*0 = NaN; |x| is < ~35 in this problem anyway.
__device__ __forceinline__ float fast_tanh(float x) {
  const float e = __expf(2.0f * fminf(x, 40.0f));
  return 1.0f - 2.0f * fast_rcp(e + 1.0f);
}

// =================== device functions (fused into mega kernels) ===================

// ---------- prep: cx[l] = C1[l,:]·x ; xF[k] = Fm[k,:]·x ; rLam = 1/Lam ----------
__device__ void dev_prep(const float* __restrict__ x, const float* __restrict__ C1,
                         const float* __restrict__ Fm, const float* __restrict__ Lam,
                         float* __restrict__ cx, float* __restrict__ xF,
                         float* __restrict__ rLam, int t) {
  float s1 = 0.f, s2 = 0.f;
  for (int i = 0; i < 256; ++i) {
    const float xi = x[i];
    s1 += C1[t * 256 + i] * xi;
    s2 += Fm[t * 256 + i] * xi;
  }
  cx[t] = s1;
  xF[t] = s2;
  rLam[t] = 1.0f / Lam[t];
}

// ---------- pack D11 chunk-triangles column-major (256 active threads) ----------
__device__ void dev_pack(const float* __restrict__ D11, float* __restrict__ cpack,
                         int t) {
  const int c = t >> 6;
  const int lane = t & 63;
  int off = 0;
  for (int li = 0; li < 63; ++li) {
    if (lane < 63 - li)
      cpack[c * CPACK_STRIDE + off + lane] =
          D11[(c * 64 + li + 1 + lane) * 256 + (c * 64 + li)];
    off += ((63 - li) + 3) & ~3;
  }
}

// ---------- blocked-panel GJ inverse of 128x128, 512 threads, 8x4 register tiles --
// A[r][c] = srcT[c*ld + r]; output dstT[c*128 + r] with the SAME element mapping as
// the load -> the only cross-step state is the a-tile, so the 8 outer steps can be
// SPLIT ACROSS KERNELS via a 64 KB global spill (measured: took mega1 from 53us
// off the critical path; each half rides alongside a batch-work kernel).
__device__ void dev_inv(const float* __restrict__ srcT, int ld,
                        float* __restrict__ dstT, int tid, int s0, int s1) {
  __shared__ float Pcols[128][20];  // [r][kk] current panel columns (pad 20)
  __shared__ float MB[128][20];     // [r][kk] panel transform M (pad 20)
  __shared__ float Ar[16][132];     // [kk][c] OLD panel-row values (pad 132)
  __shared__ float invD[16 * 20];   // [kk][j] pivot-block inverse (pad 20)
  const int ti = tid >> 5;          // 0..15  -> R = 8*ti (8 rows)
  const int tj = tid & 31;          // 0..31  -> C = 4*tj (4 cols)
  const int R = ti * 8, C = tj * 4;
  float a[8][4];
#pragma unroll
  for (int j = 0; j < 4; ++j)
#pragma unroll
    for (int g = 0; g < 2; ++g) {
      const float4 v = *(const float4*)&srcT[(C + j) * ld + (R + 4 * g)];
      a[4 * g + 0][j] = v.x; a[4 * g + 1][j] = v.y;
      a[4 * g + 2][j] = v.z; a[4 * g + 3][j] = v.w;
    }

  for (int s = s0; s < s1; ++s) {
    // ---- stage panel columns (col-tile owners) + old panel rows (row-tile owners)
    if ((tj >> 2) == s) {
      const int c0 = C - 16 * s;  // 0,4,8,12
#pragma unroll
      for (int i = 0; i < 8; ++i)
        *(float4*)&Pcols[R + i][c0] =
            make_float4(a[i][0], a[i][1], a[i][2], a[i][3]);
    }
    if ((ti >> 1) == s) {
      const int r0 = R - 16 * s;  // 0 or 8
#pragma unroll
      for (int i = 0; i < 8; ++i)
        *(float4*)&Ar[r0 + i][C] =
            make_float4(a[i][0], a[i][1], a[i][2], a[i][3]);
    }
    __syncthreads();

    // ---- 1a: invert 16x16 pivot block, 16 lanes; readlane broadcast + fast rcp
    if (tid < 16) {
      float q[16];
#pragma unroll
      for (int g = 0; g < 4; ++g) {
        const float4 v = *(const float4*)&Pcols[s * 16 + tid][4 * g];
        q[4 * g] = v.x; q[4 * g + 1] = v.y; q[4 * g + 2] = v.z; q[4 * g + 3] = v.w;
      }
#pragma unroll
      for (int kk = 0; kk < 16; ++kk) {
        float ps[16];
#pragma unroll
        for (int j = 0; j < 16; ++j)
          ps[j] = __int_as_float(
              __builtin_amdgcn_readlane(__float_as_int(q[j]), kk));
        const float piv = fast_rcp(ps[kk]);
#pragma unroll
        for (int j = 0; j < 16; ++j) ps[j] = (j == kk) ? piv : ps[j] * piv;
        const bool isP = (tid == kk);
        const float te = isP ? -1.0f : q[kk];
#pragma unroll
        for (int j = 0; j < 16; ++j) {
          const float base = (isP || j == kk) ? 0.0f : q[j];
          q[j] = base - te * ps[j];
        }
      }
#pragma unroll
      for (int g = 0; g < 4; ++g)
        *(float4*)&invD[tid * 20 + 4 * g] =
            make_float4(q[4 * g], q[4 * g + 1], q[4 * g + 2], q[4 * g + 3]);
    }
    __syncthreads();

    // ---- 1b: M[r][0..15], thread (r = tid&127, h = tid>>7) does cols 4h..4h+3 ---
    {
      const int r = tid & 127, h = tid >> 7;  // h: 0..3
      float4 mv;
      if ((r >> 4) == s) {
        mv = *(const float4*)&invD[(r & 15) * 20 + 4 * h];
      } else {
        mv = make_float4(0.f, 0.f, 0.f, 0.f);
#pragma unroll
        for (int g = 0; g < 4; ++g) {
          const float4 p = *(const float4*)&Pcols[r][4 * g];
          const float pc[4] = {p.x, p.y, p.z, p.w};
#pragma unroll
          for (int q = 0; q < 4; ++q) {
            const float4 d = *(const float4*)&invD[(4 * g + q) * 20 + 4 * h];
            mv.x -= pc[q] * d.x; mv.y -= pc[q] * d.y;
            mv.z -= pc[q] * d.z; mv.w -= pc[q] * d.w;
          }
        }
      }
      *(float4*)&MB[r][4 * h] = mv;
    }
    __syncthreads();

    // ---- phase 2: register-tiled rank-16 update ----
    if ((tj >> 2) == s) {
      // panel columns replaced by M
      const int c0 = C - 16 * s;
#pragma unroll
      for (int i = 0; i < 8; ++i) {
        const float4 m = *(const float4*)&MB[R + i][c0];
        a[i][0] = m.x; a[i][1] = m.y; a[i][2] = m.z; a[i][3] = m.w;
      }
    } else {
      if ((ti >> 1) == s) {
#pragma unroll
        for (int i = 0; i < 8; ++i)
#pragma unroll
          for (int j = 0; j < 4; ++j) a[i][j] = 0.f;
      }
#pragma unroll
      for (int half = 0; half < 2; ++half) {
        float4 ar[8];
#pragma unroll
        for (int k = 0; k < 8; ++k)
          ar[k] = *(const float4*)&Ar[half * 8 + k][C];
#pragma unroll
        for (int i = 0; i < 8; ++i) {
          const float4 m0 = *(const float4*)&MB[R + i][half * 8];
          const float4 m1 = *(const float4*)&MB[R + i][half * 8 + 4];
          const float mi[8] = {m0.x, m0.y, m0.z, m0.w, m1.x, m1.y, m1.z, m1.w};
#pragma unroll
          for (int k = 0; k < 8; ++k) {
            a[i][0] += mi[k] * ar[k].x;
            a[i][1] += mi[k] * ar[k].y;
            a[i][2] += mi[k] * ar[k].z;
            a[i][3] += mi[k] * ar[k].w;
          }
        }
      }
    }
    __syncthreads();
  }
#pragma unroll
  for (int j = 0; j < 4; ++j)
#pragma unroll
    for (int g = 0; g < 2; ++g)
      *(float4*)&dstT[(C + j) * 128 + (R + 4 * g)] = make_float4(
          a[4 * g + 0][j], a[4 * g + 1][j], a[4 * g + 2][j], a[4 * g + 3][j]);
}

// ---------- transpose u (8192x128) into vw rows 256..383 (512-thread version) ----
__device__ void dev_T(const float* __restrict__ u, float* __restrict__ vw, int bid,
                      int t) {  // t in [0,512)
  __shared__ float buf[64 * 65];
  const int b0 = bid * 64;
#pragma unroll
  for (int h = 0; h < 2; ++h) {
#pragma unroll
    for (int q = 0; q < 8; ++q) {
      const int idx = q * 512 + t;
      const int bl = idx >> 6;
      const int i2 = idx & 63;
      buf[i2 * 65 + bl] = u[(b0 + bl) * 128 + 64 * h + i2];
    }
    __syncthreads();
#pragma unroll
    for (int q = 0; q < 8; ++q) {
      const int idx = q * 512 + t;
      const int i2 = idx >> 6;
      const int bl = idx & 63;
      vw[(256 + 64 * h + i2) * NB + b0 + bl] = buf[i2 * 65 + bl];
    }
    __syncthreads();
  }
}

// ---------- vw[l][b] = cx[l] + D12[l,:]·u[b,:] via u^T, 512 threads ----------
// 8 l-rows x 2048 b per block; 128 blocks (4 b-tiles x 32 l-groups).
__device__ void dev_du512(const float* __restrict__ D12, const float* __restrict__ cx,
                          float* __restrict__ vw, int bid, int t) {
  __shared__ float Dl[8 * 128];
  const int bx = bid & 3;
  const int l0 = (bid >> 2) * 8;
#pragma unroll
  for (int q = 0; q < 2; ++q) Dl[q * 512 + t] = D12[l0 * 128 + q * 512 + t];
  __syncthreads();
  const float4* vw4 = (const float4*)vw;
  float4* vw4o = (float4*)vw;
  const int b4 = bx * 512 + t;
  float4 acc[8];
#pragma unroll
  for (int j = 0; j < 8; ++j) {
    const float cj = cx[l0 + j];
    acc[j] = make_float4(cj, cj, cj, cj);
  }
#pragma unroll 4
  for (int i = 0; i < 128; ++i) {
    const float4 wv = vw4[(256 + i) * 2048 + b4];
#pragma unroll
    for (int j = 0; j < 8; ++j) {
      const float d = Dl[j * 128 + i];
      acc[j].x += d * wv.x;
      acc[j].y += d * wv.y;
      acc[j].z += d * wv.z;
      acc[j].w += d * wv.w;
    }
  }
#pragma unroll
  for (int j = 0; j < 8; ++j) vw4o[(l0 + j) * 2048 + b4] = acc[j];
}

// ---------- W = invA11 * A12 ; z1 = invA11 * c1 ----------
__device__ void dev_WZ(const float* __restrict__ E, const float* __restrict__ C2,
                       const float* __restrict__ inv1T, float* __restrict__ W,
                       float* __restrict__ z1, int gid) {
  const int half = gid >> 14;
  const int idx = gid & 16383;
  const int j = idx >> 7;   // wave-uniform
  const int i = idx & 127;  // lane
  float s = 0.f;
  if (half == 0) {
    for (int m = 0; m < 128; ++m) s += inv1T[m * 128 + i] * E[(128 + j) * 256 + m];
    W[i * 128 + j] = s;
  } else {
    for (int m = 0; m < 128; ++m) s += inv1T[m * 128 + i] * C2[j * 256 + m];
    z1[i * 128 + j] = s;
  }
}

// ---------- S^T = (A22 - A21 W)^T ; c2p = c2 - A21 z1 ----------
__device__ void dev_SC(const float* __restrict__ E, const float* __restrict__ C2,
                       const float* __restrict__ W, const float* __restrict__ z1,
                       float* __restrict__ STt, float* __restrict__ c2p, int gid) {
  if (gid < 16384) {
    const int jj = gid >> 7;
    const int i = gid & 127;
    float s = E[(128 + jj) * 256 + 128 + i];
    for (int m = 0; m < 128; ++m) s -= E[m * 256 + 128 + i] * W[m * 128 + jj];
    STt[jj * 128 + i] = s;
  } else {
    const int idx = gid - 16384;
    const int i = idx >> 7;
    const int o = idx & 127;
    float s = C2[o * 256 + 128 + i];
    for (int m = 0; m < 128; ++m) s -= E[m * 256 + 128 + i] * z1[m * 128 + o];
    c2p[i * 128 + o] = s;
  }
}

// ---------- g2 = invS * c2p ----------
__device__ void dev_G2(const float* __restrict__ inv2T, const float* __restrict__ c2p,
                       float* __restrict__ g2, int gid) {
  const int i = gid >> 7;
  const int o = gid & 127;
  float s = 0.f;
  for (int m = 0; m < 128; ++m) s += inv2T[m * 128 + i] * c2p[m * 128 + o];
  g2[i * 128 + o] = s;
}

// ---------- g1 = z1 - W * g2 ----------
__device__ void dev_G1(const float* __restrict__ W, const float* __restrict__ z1,
                       const float* __restrict__ g2, float* __restrict__ g1, int gid) {
  const int i = gid >> 7;
  const int o = gid & 127;
  float s = z1[i * 128 + o];
  for (int m = 0; m < 128; ++m) s -= W[i * 128 + m] * g2[m * 128 + o];
  g1[i * 128 + o] = s;
}

// ---------- R = [P | Q] (128 x 384) and y0 ----------
__device__ void dev_R(const float* __restrict__ B1, const float* __restrict__ B2,
                      const float* __restrict__ D21, const float* __restrict__ D22,
                      const float* __restrict__ g1, const float* __restrict__ g2,
                      const float* __restrict__ xF, float* __restrict__ R,
                      float* __restrict__ y0, int gid) {
  if (gid < 32768) {
    const int o = gid >> 8;
    const int l = gid & 255;
    float s = D21[o * 256 + l];
    for (int m = 0; m < 128; ++m) {
      s += g1[m * 128 + o] * B1[m * 256 + l];
      s += g2[m * 128 + o] * B1[(128 + m) * 256 + l];
    }
    R[o * 384 + l] = s;
  } else if (gid < 49152) {
    const int t2 = gid - 32768;
    const int o = t2 >> 7;
    const int i = t2 & 127;
    float s = D22[o * 128 + i];
    for (int m = 0; m < 128; ++m) {
      s += g1[m * 128 + o] * B2[m * 128 + i];
      s += g2[m * 128 + o] * B2[(128 + m) * 128 + i];
    }
    R[o * 384 + 256 + i] = s;
  } else if (gid < 49280) {
    const int o = gid - 49152;
    float s = 0.f;
    for (int m = 0; m < 128; ++m) {
      s += g1[m * 128 + o] * xF[m];
      s += g2[m * 128 + o] * xF[128 + m];
    }
    y0[o] = s;
  }
}

// ---------- right-looking 64-step scan chunk: v[64] in REGISTERS ----------
// MEASURED (R7): LDS-staging cpack+rLam (one coalesced pass, 512 threads) took
// the scan kernels out of the top-5 (-24us wall) -- the 64 serial steps were
// stalled on per-step global load latency at 1 wave/SIMD.
__device__ void dev_scan(const float* __restrict__ cpack,
                         const float* __restrict__ rLam, float* __restrict__ vw,
                         int c, int bid, int t) {
  __shared__ float sc[CPACK_STRIDE];  // 8704 B
  __shared__ float srl[64];
  for (int i = t; i < CPACK_STRIDE; i += 512) sc[i] = cpack[c * CPACK_STRIDE + i];
  if (t < 64) srl[t] = rLam[c * 64 + t];
  __syncthreads();
  if (t >= 256) return;

  const int b = bid * 256 + t;
  const int l0 = c * 64;
  const float4* cp4 = (const float4*)sc;
  float v[64];
#pragma unroll
  for (int li = 0; li < 64; ++li) v[li] = vw[(l0 + li) * NB + b];
  sfor<64>([&](auto LI) {
    constexpr int li = decltype(LI)::value;
    const float w = fast_tanh(v[li] * srl[li]);
    vw[(l0 + li) * NB + b] = w;  // fire-and-forget
    constexpr int n = 63 - li;
    constexpr int off4 = coff(li) / 4;
    sfor<(n + 3) / 4>([&](auto Q) {
      constexpr int q = decltype(Q)::value;
      const float4 d = cp4[off4 + q];
      if constexpr (4 * q + 0 < n) v[li + 1 + 4 * q + 0] += d.x * w;
      if constexpr (4 * q + 1 < n) v[li + 1 + 4 * q + 1] += d.y * w;
      if constexpr (4 * q + 2 < n) v[li + 1 + 4 * q + 2] += d.z * w;
      if constexpr (4 * q + 3 < n) v[li + 1 + 4 * q + 3] += d.w * w;
    });
  });
}

// ---------- cross-chunk rank-64 update (role = old 256-thread block id) ----------
__device__ void dev_upd(const float* __restrict__ D11, float* __restrict__ vw, int c,
                        int role, int lane) {
  float4* vw4 = (float4*)vw;
  const int b4 = (role & 7) * 256 + lane;
  const int lp0 = (c + 1) * 64 + (role >> 3) * 8;
  const int k0 = c * 64;
  float4 acc[8];
#pragma unroll
  for (int j = 0; j < 8; ++j) acc[j] = vw4[(lp0 + j) * 2048 + b4];
  for (int k = 0; k < 64; ++k) {
    const float4 wv = vw4[(k0 + k) * 2048 + b4];
#pragma unroll
    for (int j = 0; j < 8; ++j) {
      const float d = D11[(lp0 + j) * 256 + k0 + k];  // wave-uniform scalar
      acc[j].x += d * wv.x;
      acc[j].y += d * wv.y;
      acc[j].z += d * wv.z;
      acc[j].w += d * wv.w;
    }
  }
#pragma unroll
  for (int j = 0; j < 8; ++j) vw4[(lp0 + j) * 2048 + b4] = acc[j];
}

// =================== mega kernels (block-range dispatch) ===================
//   k1: T + prep + pack + inv1[0:4]     k6: upd1 + inv2[4:8]
//   k2: du  + inv1[4:8]                 k7: scan2 + G2
//   k3: scan0 + WZ                      k8: upd2 + G1
//   k4: upd0 + SC                       k9: scan3 + R
//   k5: scan1 + inv2[0:4]              k10: k_y (in-block k-split, LDS combine)

__global__ __launch_bounds__(512) void mega1(const float* u, const float* x,
                                             const float* C1, const float* Fm,
                                             const float* Lam, const float* D11,
                                             const float* E, float* vw, float* cx,
                                             float* xF, float* rLam, float* cpack,
                                             float* invSt) {
  const int bid = blockIdx.x;
  const int t = threadIdx.x;
  if (bid < 128) {
    dev_T(u, vw, bid, t);  // all 512 threads participate (internal barriers)
  } else if (bid == 128) {
    if (t < 256) dev_prep(x, C1, Fm, Lam, cx, xF, rLam, t);  // no barriers inside
  } else if (bid == 129) {
    if (t < 256) dev_pack(D11, cpack, t);  // no barriers inside
  } else {
    dev_inv(E, 256, invSt, t, 0, 4);  // bid == 130: inv1 first half
  }
}

__global__ __launch_bounds__(512) void mega2(const float* D12, const float* cx,
                                             float* vw, const float* invSt,
                                             float* inv1T) {
  const int bid = blockIdx.x;
  const int t = threadIdx.x;
  if (bid < 128) dev_du512(D12, cx, vw, bid, t);
  else dev_inv(invSt, 128, inv1T, t, 4, 8);  // bid == 128: inv1 second half
}

__global__ __launch_bounds__(512) void mega3(const float* cpack, const float* rLam,
                                             float* vw, const float* E,
                                             const float* C2, const float* inv1T,
                                             float* W, float* z1) {
  const int bid = blockIdx.x;
  const int t = threadIdx.x;
  if (bid < 32) {
    dev_scan(cpack, rLam, vw, 0, bid, t);  // all 512 stage; t<256 run recurrence
  } else {
    dev_WZ(E, C2, inv1T, W, z1, (bid - 32) * 512 + t);  // 64 blocks
  }
}

__global__ __launch_bounds__(512) void mega4(const float* D11, float* vw,
                                             const float* E, const float* C2,
                                             const float* W, const float* z1,
                                             float* STt, float* c2p) {
  const int bid = blockIdx.x;
  const int t = threadIdx.x;
  if (bid < 96) dev_upd(D11, vw, 0, bid * 2 + (t >> 8), t & 255);  // roles 0..191
  else dev_SC(E, C2, W, z1, STt, c2p, (bid - 96) * 512 + t);       // 64 blocks
}

__global__ __launch_bounds__(512) void mega5(const float* cpack, const float* rLam,
                                             float* vw, const float* STt,
                                             float* inv2St) {
  const int bid = blockIdx.x;
  const int t = threadIdx.x;
  if (bid < 32) {
    dev_scan(cpack, rLam, vw, 1, bid, t);
  } else {
    dev_inv(STt, 128, inv2St, t, 0, 4);  // bid == 32: inv2 first half
  }
}

__global__ __launch_bounds__(512) void mega6(const float* D11, float* vw,
                                             const float* inv2St, float* inv2T) {
  const int bid = blockIdx.x;
  const int t = threadIdx.x;
  if (bid < 64) dev_upd(D11, vw, 1, bid * 2 + (t >> 8), t & 255);  // roles 0..127
  else dev_inv(inv2St, 128, inv2T, t, 4, 8);  // bid == 64: inv2 second half
}

__global__ __launch_bounds__(512) void mega7(const float* cpack, const float* rLam,
                                             float* vw, const float* inv2T,
                                             const float* c2p, float* g2) {
  const int bid = blockIdx.x;
  const int t = threadIdx.x;
  if (bid < 32) {
    dev_scan(cpack, rLam, vw, 2, bid, t);
  } else {
    dev_G2(inv2T, c2p, g2, (bid - 32) * 512 + t);  // 32 blocks
  }
}

__global__ __launch_bounds__(512) void mega8(const float* D11, float* vw,
                                             const float* W, const float* z1,
                                             const float* g2, float* g1) {
  const int bid = blockIdx.x;
  const int t = threadIdx.x;
  if (bid < 32) dev_upd(D11, vw, 2, bid * 2 + (t >> 8), t & 255);  // roles 0..63
  else dev_G1(W, z1, g2, g1, (bid - 32) * 512 + t);  // 32 blocks
}

__global__ __launch_bounds__(512) void mega9(const float* cpack, const float* rLam,
                                             float* vw, const float* B1,
                                             const float* B2, const float* D21,
                                             const float* D22, const float* g1,
                                             const float* g2, const float* xF,
                                             float* R, float* y0) {
  const int bid = blockIdx.x;
  const int t = threadIdx.x;
  if (bid < 32) {
    dev_scan(cpack, rLam, vw, 3, bid, t);
  } else {
    dev_R(B1, B2, D21, D22, g1, g2, xF, R, y0, (bid - 32) * 512 + t);  // 97 blk
  }
}

// ---------- y[b][o] = y0[o] + sum_{k<384} R[o][k] vw[k][b] ----------
// v4 (post-mortem R12): global atomicAdd on y was catastrophic -- cross-XCD
// device-scope atomics resolve at HBM (WRITE_SIZE 4->64MB, k_y 47.7->133.7us).
// Keep the traffic-halving (o-tile 4 -> ~400MB L3 reads vs measured ~17TB/s
// ceiling) but k-split WITHIN the block: 512 threads, ks = t>>8 covers 192 k's
// of the same vw column; ks=1 dumps 16 partials to LDS; ks=0 combines + y0 and
// does plain float4 stores. MLP per SIMD identical to the measured-good R6
// config (2 waves/SIMD x 8 loads in flight). Zero atomics.
__global__ __launch_bounds__(512) void k_y(const float* __restrict__ vw,
                                           const float* __restrict__ R,
                                           const float* __restrict__ y0,
                                           float* __restrict__ y) {
  __shared__ float Rl[1536];        // [j][k] 4 x 384
  __shared__ float part[256 * 16];  // ks=1 partials: [lane][bi*4+j]
  const int tid = threadIdx.x;      // 0..511
  const int bid = blockIdx.x;       // 256 blocks
  const int gx = bid & 7;           // b-tile (XCD-aligned)
  const int gy = bid >> 3;          // o-tile, 0..31
  const int o0 = gy * 4;
#pragma unroll
  for (int q = 0; q < 3; ++q) Rl[q * 512 + tid] = R[o0 * 384 + q * 512 + tid];
  __syncthreads();

  const int lane = tid & 255;
  const int ks = tid >> 8;  // k-half, 0..1
  const int kbase = ks * 192;
  const float4* vw4 = (const float4*)vw;
  const int b4 = gx * 256 + lane;
  float acc[4][4];
#pragma unroll
  for (int j = 0; j < 4; ++j)
#pragma unroll
    for (int bi = 0; bi < 4; ++bi) acc[bi][j] = 0.f;

  for (int k = 0; k < 192; k += 8) {
    float4 w[8];
#pragma unroll
    for (int kk = 0; kk < 8; ++kk) w[kk] = vw4[(kbase + k + kk) * 2048 + b4];
#pragma unroll
    for (int j = 0; j < 4; ++j) {
      const float4 r0 = *(const float4*)&Rl[j * 384 + kbase + k];
      const float4 r1 = *(const float4*)&Rl[j * 384 + kbase + k + 4];
      acc[0][j] += r0.x * w[0].x + r0.y * w[1].x + r0.z * w[2].x + r0.w * w[3].x +
                   r1.x * w[4].x + r1.y * w[5].x + r1.z * w[6].x + r1.w * w[7].x;
      acc[1][j] += r0.x * w[0].y + r0.y * w[1].y + r0.z * w[2].y + r0.w * w[3].y +
                   r1.x * w[4].y + r1.y * w[5].y + r1.z * w[6].y + r1.w * w[7].y;
      acc[2][j] += r0.x * w[0].z + r0.y * w[1].z + r0.z * w[2].z + r0.w * w[3].z +
                   r1.x * w[4].z + r1.y * w[5].z + r1.z * w[6].z + r1.w * w[7].z;
      acc[3][j] += r0.x * w[0].w + r0.y * w[1].w + r0.z * w[2].w + r0.w * w[3].w +
                   r1.x * w[4].w + r1.y * w[5].w + r1.z * w[6].w + r1.w * w[7].w;
    }
  }

  if (ks == 1) {
#pragma unroll
    for (int bi = 0; bi < 4; ++bi)
      *(float4*)&part[lane * 16 + bi * 4] =
          make_float4(acc[bi][0], acc[bi][1], acc[bi][2], acc[bi][3]);
  }
  __syncthreads();
  if (ks == 0) {
    const int b0 = b4 * 4;
#pragma unroll
    for (int bi = 0; bi < 4; ++bi) {
      const float4 p = *(const float4*)&part[lane * 16 + bi * 4];
      *(float4*)&y[(b0 + bi) * 128 + o0] =
          make_float4(acc[bi][0] + p.x + y0[o0 + 0],
                      acc[bi][1] + p.y + y0[o0 + 1],
                      acc[bi][2] + p.z + y0[o0 + 2],
                      acc[bi][3] + p.w + y0[o0 + 3]);
    }
  }
}

extern "C" void kernel_launch(void* const* d_in, const int* in_sizes, int n_in,
                              void* d_out, int out_size, void* d_ws, size_t ws_size,
                              hipStream_t stream) {
  const float* u   = (const float*)d_in[0];   // (8192,1,128)
  const float* x   = (const float*)d_in[1];   // (1,1,256)
  const float* Fm  = (const float*)d_in[2];   // (256,256)
  const float* B1  = (const float*)d_in[3];   // (256,256)
  const float* B2  = (const float*)d_in[4];   // (256,128)
  const float* C1  = (const float*)d_in[5];   // (256,256)
  const float* C2  = (const float*)d_in[6];   // (128,256)
  const float* D11 = (const float*)d_in[7];   // (256,256) strictly lower
  const float* D12 = (const float*)d_in[8];   // (256,128)
  const float* D21 = (const float*)d_in[9];   // (128,256)
  const float* D22 = (const float*)d_in[10];  // (128,128)
  const float* E   = (const float*)d_in[11];  // (256,256)
  const float* Lam = (const float*)d_in[12];  // (256,)
  float* y = (float*)d_out;                   // (8192,1,128) fp32

  float* F = (float*)d_ws;                     // ~13.4 MB used
  float* vw    = F;                            // 384*8192 (rows 256..383 = u^T)
  float* SMb   = F + 384 * NB;
  float* inv1T = SMb;                          // 16384
  float* Wm    = SMb + 16384;
  float* z1    = SMb + 32768;
  float* STt   = SMb + 49152;
  float* c2p   = SMb + 65536;
  float* inv2T = SMb + 81920;
  float* g2    = SMb + 98304;
  float* g1    = SMb + 114688;
  float* Rm    = SMb + 131072;                 // 128*384
  float* y0v   = SMb + 180224;                 // 128
  float* cx    = SMb + 180352;                 // 256
  float* xF    = SMb + 180608;                 // 256
  float* rLam  = SMb + 180864;                 // 256
  float* cpack = SMb + 181120;                 // 4*2176
  // inverse mid-state spills ALIAS dead regions (footprint unchanged):
  // invSt (inv1 state, live k1->k2) reuses STt (first written in k4);
  // inv2St (inv2 state, live k5->k6) reuses g1 (first written in k8).
  float* invSt  = STt;
  float* inv2St = g1;

  mega1<<<131, 512, 0, stream>>>(u, x, C1, Fm, Lam, D11, E, vw, cx, xF, rLam,
                                 cpack, invSt);
  mega2<<<129, 512, 0, stream>>>(D12, cx, vw, invSt, inv1T);
  mega3<<<96, 512, 0, stream>>>(cpack, rLam, vw, E, C2, inv1T, Wm, z1);
  mega4<<<160, 512, 0, stream>>>(D11, vw, E, C2, Wm, z1, STt, c2p);
  mega5<<<33, 512, 0, stream>>>(cpack, rLam, vw, STt, inv2St);
  mega6<<<65, 512, 0, stream>>>(D11, vw, inv2St, inv2T);
  mega7<<<64, 512, 0, stream>>>(cpack, rLam, vw, inv2T, c2p, g2);
  mega8<<<64, 512, 0, stream>>>(D11, vw, Wm, z1, g2, g1);
  mega9<<<129, 512, 0, stream>>>(cpack, rLam, vw, B1, B2, D21, D22, g1, g2, xF,
                                 Rm, y0v);
  k_y<<<256, 512, 0, stream>>>(vw, Rm, y0v, y);
}

// Round 18
// 301.797 us; speedup vs baseline: 1.3732x; 1.0635x over previous
//
#include <hip/hip_runtime.h>
#include <utility>

// Problem constants
// DIM_IN=128, DIM_OUT=128, DIM_X=256, L=256, BATCH=8192, fp32 everywhere.
#define NB 8192

// ---------- static_for helper (compile-time register indices) ----------
template <typename F, size_t... I>
__device__ __forceinline__ void sfor_impl(F&& f, std::index_sequence<I...>) {
  (f(std::integral_constant<int, (int)I>{}), ...);
}
template <int N, typename F>
__device__ __forceinline__ void sfor(F&& f) {
  sfor_impl((F&&)f, std::make_index_sequence<N>{});
}

// packed-column-triangle offset: column li holds D[l2][li], l2=li+1..63, padded to x4
constexpr int coff(int li) {
  int o = 0;
  for (int j = 0; j < li; ++j) o += ((63 - j) + 3) & ~3;
  return o;
}
#define CPACK_STRIDE 2176  // > coff(63), float4-aligned

// fast reciprocal: v_rcp_f32 + one Newton step (~1 ulp). Avoids the ~10-instr
// IEEE divide sequence on serial critical paths (GJ pivot chain, tanh chain).
__device__ __forceinline__ float fast_rcp(float x) {
  float r = __builtin_amdgcn_rcpf(x);
  return r * (2.0f - x * r);
}

// fast tanh: 1 - 2/(exp(2x)+1). Clamp keeps e finite so the rcp Newton step
// can't see inf*0 = NaN; |x| is < ~35 in this problem anyway.
__device__ __forceinline__ float fast_tanh(float x) {
  const float e = __expf(2.0f * fminf(x, 40.0f));
  return 1.0f - 2.0f * fast_rcp(e + 1.0f);
}

// =================== device functions (fused into mega kernels) ===================

// ---------- prep: cx[l] = C1[l,:]·x ; xF[k] = Fm[k,:]·x ; rLam = 1/Lam ----------
__device__ void dev_prep(const float* __restrict__ x, const float* __restrict__ C1,
                         const float* __restrict__ Fm, const float* __restrict__ Lam,
                         float* __restrict__ cx, float* __restrict__ xF,
                         float* __restrict__ rLam, int t) {
  float s1 = 0.f, s2 = 0.f;
  for (int i = 0; i < 256; ++i) {
    const float xi = x[i];
    s1 += C1[t * 256 + i] * xi;
    s2 += Fm[t * 256 + i] * xi;
  }
  cx[t] = s1;
  xF[t] = s2;
  rLam[t] = 1.0f / Lam[t];
}

// ---------- pack D11 chunk-triangles column-major (256 active threads) ----------
__device__ void dev_pack(const float* __restrict__ D11, float* __restrict__ cpack,
                         int t) {
  const int c = t >> 6;
  const int lane = t & 63;
  int off = 0;
  for (int li = 0; li < 63; ++li) {
    if (lane < 63 - li)
      cpack[c * CPACK_STRIDE + off + lane] =
          D11[(c * 64 + li + 1 + lane) * 256 + (c * 64 + li)];
    off += ((63 - li) + 3) & ~3;
  }
}

// ---------- blocked-panel GJ inverse of 128x128, 512 threads, 8x4 register tiles --
// A[r][c] = srcT[c*ld + r]; output dstT[c*128 + r] with the SAME element mapping as
// the load -> the only cross-step state is the a-tile, so the 8 outer steps can be
// SPLIT ACROSS KERNELS via a 64 KB global spill (measured: took mega1 from 53us
// off the critical path; each half rides alongside a batch-work kernel).
__device__ void dev_inv(const float* __restrict__ srcT, int ld,
                        float* __restrict__ dstT, int tid, int s0, int s1) {
  __shared__ float Pcols[128][20];  // [r][kk] current panel columns (pad 20)
  __shared__ float MB[128][20];     // [r][kk] panel transform M (pad 20)
  __shared__ float Ar[16][132];     // [kk][c] OLD panel-row values (pad 132)
  __shared__ float invD[16 * 20];   // [kk][j] pivot-block inverse (pad 20)
  const int ti = tid >> 5;          // 0..15  -> R = 8*ti (8 rows)
  const int tj = tid & 31;          // 0..31  -> C = 4*tj (4 cols)
  const int R = ti * 8, C = tj * 4;
  float a[8][4];
#pragma unroll
  for (int j = 0; j < 4; ++j)
#pragma unroll
    for (int g = 0; g < 2; ++g) {
      const float4 v = *(const float4*)&srcT[(C + j) * ld + (R + 4 * g)];
      a[4 * g + 0][j] = v.x; a[4 * g + 1][j] = v.y;
      a[4 * g + 2][j] = v.z; a[4 * g + 3][j] = v.w;
    }

  for (int s = s0; s < s1; ++s) {
    // ---- stage panel columns (col-tile owners) + old panel rows (row-tile owners)
    if ((tj >> 2) == s) {
      const int c0 = C - 16 * s;  // 0,4,8,12
#pragma unroll
      for (int i = 0; i < 8; ++i)
        *(float4*)&Pcols[R + i][c0] =
            make_float4(a[i][0], a[i][1], a[i][2], a[i][3]);
    }
    if ((ti >> 1) == s) {
      const int r0 = R - 16 * s;  // 0 or 8
#pragma unroll
      for (int i = 0; i < 8; ++i)
        *(float4*)&Ar[r0 + i][C] =
            make_float4(a[i][0], a[i][1], a[i][2], a[i][3]);
    }
    __syncthreads();

    // ---- 1a: invert 16x16 pivot block, 16 lanes; readlane broadcast + fast rcp
    if (tid < 16) {
      float q[16];
#pragma unroll
      for (int g = 0; g < 4; ++g) {
        const float4 v = *(const float4*)&Pcols[s * 16 + tid][4 * g];
        q[4 * g] = v.x; q[4 * g + 1] = v.y; q[4 * g + 2] = v.z; q[4 * g + 3] = v.w;
      }
#pragma unroll
      for (int kk = 0; kk < 16; ++kk) {
        float ps[16];
#pragma unroll
        for (int j = 0; j < 16; ++j)
          ps[j] = __int_as_float(
              __builtin_amdgcn_readlane(__float_as_int(q[j]), kk));
        const float piv = fast_rcp(ps[kk]);
#pragma unroll
        for (int j = 0; j < 16; ++j) ps[j] = (j == kk) ? piv : ps[j] * piv;
        const bool isP = (tid == kk);
        const float te = isP ? -1.0f : q[kk];
#pragma unroll
        for (int j = 0; j < 16; ++j) {
          const float base = (isP || j == kk) ? 0.0f : q[j];
          q[j] = base - te * ps[j];
        }
      }
#pragma unroll
      for (int g = 0; g < 4; ++g)
        *(float4*)&invD[tid * 20 + 4 * g] =
            make_float4(q[4 * g], q[4 * g + 1], q[4 * g + 2], q[4 * g + 3]);
    }
    __syncthreads();

    // ---- 1b: M[r][0..15], thread (r = tid&127, h = tid>>7) does cols 4h..4h+3 ---
    {
      const int r = tid & 127, h = tid >> 7;  // h: 0..3
      float4 mv;
      if ((r >> 4) == s) {
        mv = *(const float4*)&invD[(r & 15) * 20 + 4 * h];
      } else {
        mv = make_float4(0.f, 0.f, 0.f, 0.f);
#pragma unroll
        for (int g = 0; g < 4; ++g) {
          const float4 p = *(const float4*)&Pcols[r][4 * g];
          const float pc[4] = {p.x, p.y, p.z, p.w};
#pragma unroll
          for (int q = 0; q < 4; ++q) {
            const float4 d = *(const float4*)&invD[(4 * g + q) * 20 + 4 * h];
            mv.x -= pc[q] * d.x; mv.y -= pc[q] * d.y;
            mv.z -= pc[q] * d.z; mv.w -= pc[q] * d.w;
          }
        }
      }
      *(float4*)&MB[r][4 * h] = mv;
    }
    __syncthreads();

    // ---- phase 2: register-tiled rank-16 update ----
    if ((tj >> 2) == s) {
      // panel columns replaced by M
      const int c0 = C - 16 * s;
#pragma unroll
      for (int i = 0; i < 8; ++i) {
        const float4 m = *(const float4*)&MB[R + i][c0];
        a[i][0] = m.x; a[i][1] = m.y; a[i][2] = m.z; a[i][3] = m.w;
      }
    } else {
      if ((ti >> 1) == s) {
#pragma unroll
        for (int i = 0; i < 8; ++i)
#pragma unroll
          for (int j = 0; j < 4; ++j) a[i][j] = 0.f;
      }
#pragma unroll
      for (int half = 0; half < 2; ++half) {
        float4 ar[8];
#pragma unroll
        for (int k = 0; k < 8; ++k)
          ar[k] = *(const float4*)&Ar[half * 8 + k][C];
#pragma unroll
        for (int i = 0; i < 8; ++i) {
          const float4 m0 = *(const float4*)&MB[R + i][half * 8];
          const float4 m1 = *(const float4*)&MB[R + i][half * 8 + 4];
          const float mi[8] = {m0.x, m0.y, m0.z, m0.w, m1.x, m1.y, m1.z, m1.w};
#pragma unroll
          for (int k = 0; k < 8; ++k) {
            a[i][0] += mi[k] * ar[k].x;
            a[i][1] += mi[k] * ar[k].y;
            a[i][2] += mi[k] * ar[k].z;
            a[i][3] += mi[k] * ar[k].w;
          }
        }
      }
    }
    __syncthreads();
  }
#pragma unroll
  for (int j = 0; j < 4; ++j)
#pragma unroll
    for (int g = 0; g < 2; ++g)
      *(float4*)&dstT[(C + j) * 128 + (R + 4 * g)] = make_float4(
          a[4 * g + 0][j], a[4 * g + 1][j], a[4 * g + 2][j], a[4 * g + 3][j]);
}

// ---------- transpose u (8192x128) into vw rows 256..383 (512-thread version) ----
__device__ void dev_T(const float* __restrict__ u, float* __restrict__ vw, int bid,
                      int t) {  // t in [0,512)
  __shared__ float buf[64 * 65];
  const int b0 = bid * 64;
#pragma unroll
  for (int h = 0; h < 2; ++h) {
#pragma unroll
    for (int q = 0; q < 8; ++q) {
      const int idx = q * 512 + t;
      const int bl = idx >> 6;
      const int i2 = idx & 63;
      buf[i2 * 65 + bl] = u[(b0 + bl) * 128 + 64 * h + i2];
    }
    __syncthreads();
#pragma unroll
    for (int q = 0; q < 8; ++q) {
      const int idx = q * 512 + t;
      const int i2 = idx >> 6;
      const int bl = idx & 63;
      vw[(256 + 64 * h + i2) * NB + b0 + bl] = buf[i2 * 65 + bl];
    }
    __syncthreads();
  }
}

// ---------- vw[l][b] = cx[l] + D12[l,:]·u[b,:]  (GEMM-style, LDS-tiled) ----------
// v2 (post-mortem R17): direct-read du was mega2's 42.5us long pole -- 3TB/s
// effective L3 (32x redundant reads of the 4MB u^T, low MLP on 128 CUs), vs
// inv-half ~26us. LDS-tile: 128 blocks = 16 l-groups (16 rows) x 8 b-tiles
// (1024 b). u^T staged in 16 chunks of 8 i x 256 float4 (32KB LDS); D12 tile
// (16x128, 8KB) staged once. Unique L3 reads halve to 64MB; redundancy moves
// to LDS. i-summation order unchanged -> bit-identical output.
__device__ void dev_du512(const float* __restrict__ D12, const float* __restrict__ cx,
                          float* __restrict__ vw, int bid, int t) {
  __shared__ float4 ut[8][256];   // 32 KB: 8 i-rows x 256 float4
  __shared__ float Dl[16 * 128];  // 8 KB: 16 l-rows x 128 i
  const int bx = bid & 7;          // b-tile: 256 float4 (1024 floats)
  const int l0 = (bid >> 3) * 16;  // 16 l-rows per block
  const int tt = t & 255;
  const int lh = t >> 8;  // l-half: rows l0+lh*8 .. l0+lh*8+7
  // stage D12 tile once: 2048 floats, 4 per thread (visible after 1st barrier)
#pragma unroll
  for (int q = 0; q < 4; ++q) {
    const int e = q * 512 + t;
    Dl[e] = D12[(l0 + (e >> 7)) * 128 + (e & 127)];
  }
  const float4* vw4 = (const float4*)vw;
  float4* vw4o = (float4*)vw;
  const int b4 = bx * 256 + tt;
  float4 acc[8];
#pragma unroll
  for (int j = 0; j < 8; ++j) {
    const float cj = cx[l0 + lh * 8 + j];
    acc[j] = make_float4(cj, cj, cj, cj);
  }
  for (int kc = 0; kc < 16; ++kc) {
    __syncthreads();  // prior chunk fully consumed (and Dl visible on kc==0)
#pragma unroll
    for (int q = 0; q < 4; ++q) {
      const int e = q * 512 + t;
      ut[e >> 8][e & 255] =
          vw4[(256 + kc * 8 + (e >> 8)) * 2048 + bx * 256 + (e & 255)];
    }
    __syncthreads();
#pragma unroll
    for (int i2 = 0; i2 < 8; ++i2) {
      const float4 w = ut[i2][tt];
#pragma unroll
      for (int j = 0; j < 8; ++j) {
        const float d = Dl[(lh * 8 + j) * 128 + kc * 8 + i2];
        acc[j].x += d * w.x;
        acc[j].y += d * w.y;
        acc[j].z += d * w.z;
        acc[j].w += d * w.w;
      }
    }
  }
#pragma unroll
  for (int j = 0; j < 8; ++j) vw4o[(l0 + lh * 8 + j) * 2048 + b4] = acc[j];
}

// ---------- W = invA11 * A12 ; z1 = invA11 * c1 ----------
__device__ void dev_WZ(const float* __restrict__ E, const float* __restrict__ C2,
                       const float* __restrict__ inv1T, float* __restrict__ W,
                       float* __restrict__ z1, int gid) {
  const int half = gid >> 14;
  const int idx = gid & 16383;
  const int j = idx >> 7;   // wave-uniform
  const int i = idx & 127;  // lane
  float s = 0.f;
  if (half == 0) {
    for (int m = 0; m < 128; ++m) s += inv1T[m * 128 + i] * E[(128 + j) * 256 + m];
    W[i * 128 + j] = s;
  } else {
    for (int m = 0; m < 128; ++m) s += inv1T[m * 128 + i] * C2[j * 256 + m];
    z1[i * 128 + j] = s;
  }
}

// ---------- S^T = (A22 - A21 W)^T ; c2p = c2 - A21 z1 ----------
__device__ void dev_SC(const float* __restrict__ E, const float* __restrict__ C2,
                       const float* __restrict__ W, const float* __restrict__ z1,
                       float* __restrict__ STt, float* __restrict__ c2p, int gid) {
  if (gid < 16384) {
    const int jj = gid >> 7;
    const int i = gid & 127;
    float s = E[(128 + jj) * 256 + 128 + i];
    for (int m = 0; m < 128; ++m) s -= E[m * 256 + 128 + i] * W[m * 128 + jj];
    STt[jj * 128 + i] = s;
  } else {
    const int idx = gid - 16384;
    const int i = idx >> 7;
    const int o = idx & 127;
    float s = C2[o * 256 + 128 + i];
    for (int m = 0; m < 128; ++m) s -= E[m * 256 + 128 + i] * z1[m * 128 + o];
    c2p[i * 128 + o] = s;
  }
}

// ---------- g2 = invS * c2p ----------
__device__ void dev_G2(const float* __restrict__ inv2T, const float* __restrict__ c2p,
                       float* __restrict__ g2, int gid) {
  const int i = gid >> 7;
  const int o = gid & 127;
  float s = 0.f;
  for (int m = 0; m < 128; ++m) s += inv2T[m * 128 + i] * c2p[m * 128 + o];
  g2[i * 128 + o] = s;
}

// ---------- g1 = z1 - W * g2 ----------
__device__ void dev_G1(const float* __restrict__ W, const float* __restrict__ z1,
                       const float* __restrict__ g2, float* __restrict__ g1, int gid) {
  const int i = gid >> 7;
  const int o = gid & 127;
  float s = z1[i * 128 + o];
  for (int m = 0; m < 128; ++m) s -= W[i * 128 + m] * g2[m * 128 + o];
  g1[i * 128 + o] = s;
}

// ---------- R = [P | Q] (128 x 384) and y0 ----------
__device__ void dev_R(const float* __restrict__ B1, const float* __restrict__ B2,
                      const float* __restrict__ D21, const float* __restrict__ D22,
                      const float* __restrict__ g1, const float* __restrict__ g2,
                      const float* __restrict__ xF, float* __restrict__ R,
                      float* __restrict__ y0, int gid) {
  if (gid < 32768) {
    const int o = gid >> 8;
    const int l = gid & 255;
    float s = D21[o * 256 + l];
    for (int m = 0; m < 128; ++m) {
      s += g1[m * 128 + o] * B1[m * 256 + l];
      s += g2[m * 128 + o] * B1[(128 + m) * 256 + l];
    }
    R[o * 384 + l] = s;
  } else if (gid < 49152) {
    const int t2 = gid - 32768;
    const int o = t2 >> 7;
    const int i = t2 & 127;
    float s = D22[o * 128 + i];
    for (int m = 0; m < 128; ++m) {
      s += g1[m * 128 + o] * B2[m * 128 + i];
      s += g2[m * 128 + o] * B2[(128 + m) * 128 + i];
    }
    R[o * 384 + 256 + i] = s;
  } else if (gid < 49280) {
    const int o = gid - 49152;
    float s = 0.f;
    for (int m = 0; m < 128; ++m) {
      s += g1[m * 128 + o] * xF[m];
      s += g2[m * 128 + o] * xF[128 + m];
    }
    y0[o] = s;
  }
}

// ---------- right-looking 64-step scan chunk: v[64] in REGISTERS ----------
// MEASURED (R7): LDS-staging cpack+rLam (one coalesced pass, 512 threads) took
// the scan kernels out of the top-5 (-24us wall) -- the 64 serial steps were
// stalled on per-step global load latency at 1 wave/SIMD.
__device__ void dev_scan(const float* __restrict__ cpack,
                         const float* __restrict__ rLam, float* __restrict__ vw,
                         int c, int bid, int t) {
  __shared__ float sc[CPACK_STRIDE];  // 8704 B
  __shared__ float srl[64];
  for (int i = t; i < CPACK_STRIDE; i += 512) sc[i] = cpack[c * CPACK_STRIDE + i];
  if (t < 64) srl[t] = rLam[c * 64 + t];
  __syncthreads();
  if (t >= 256) return;

  const int b = bid * 256 + t;
  const int l0 = c * 64;
  const float4* cp4 = (const float4*)sc;
  float v[64];
#pragma unroll
  for (int li = 0; li < 64; ++li) v[li] = vw[(l0 + li) * NB + b];
  sfor<64>([&](auto LI) {
    constexpr int li = decltype(LI)::value;
    const float w = fast_tanh(v[li] * srl[li]);
    vw[(l0 + li) * NB + b] = w;  // fire-and-forget
    constexpr int n = 63 - li;
    constexpr int off4 = coff(li) / 4;
    sfor<(n + 3) / 4>([&](auto Q) {
      constexpr int q = decltype(Q)::value;
      const float4 d = cp4[off4 + q];
      if constexpr (4 * q + 0 < n) v[li + 1 + 4 * q + 0] += d.x * w;
      if constexpr (4 * q + 1 < n) v[li + 1 + 4 * q + 1] += d.y * w;
      if constexpr (4 * q + 2 < n) v[li + 1 + 4 * q + 2] += d.z * w;
      if constexpr (4 * q + 3 < n) v[li + 1 + 4 * q + 3] += d.w * w;
    });
  });
}

// ---------- cross-chunk rank-64 update (role = old 256-thread block id) ----------
__device__ void dev_upd(const float* __restrict__ D11, float* __restrict__ vw, int c,
                        int role, int lane) {
  float4* vw4 = (float4*)vw;
  const int b4 = (role & 7) * 256 + lane;
  const int lp0 = (c + 1) * 64 + (role >> 3) * 8;
  const int k0 = c * 64;
  float4 acc[8];
#pragma unroll
  for (int j = 0; j < 8; ++j) acc[j] = vw4[(lp0 + j) * 2048 + b4];
  for (int k = 0; k < 64; ++k) {
    const float4 wv = vw4[(k0 + k) * 2048 + b4];
#pragma unroll
    for (int j = 0; j < 8; ++j) {
      const float d = D11[(lp0 + j) * 256 + k0 + k];  // wave-uniform scalar
      acc[j].x += d * wv.x;
      acc[j].y += d * wv.y;
      acc[j].z += d * wv.z;
      acc[j].w += d * wv.w;
    }
  }
#pragma unroll
  for (int j = 0; j < 8; ++j) vw4[(lp0 + j) * 2048 + b4] = acc[j];
}

// =================== mega kernels (block-range dispatch) ===================
//   k1: T + prep + pack + inv1[0:4]     k6: upd1 + inv2[4:8]
//   k2: du(LDS-tiled) + inv1[4:8]       k7: scan2 + G2
//   k3: scan0 + WZ                      k8: upd2 + G1
//   k4: upd0 + SC                       k9: scan3 + R
//   k5: scan1 + inv2[0:4]              k10: k_y (in-block k-split, LDS combine)

__global__ __launch_bounds__(512) void mega1(const float* u, const float* x,
                                             const float* C1, const float* Fm,
                                             const float* Lam, const float* D11,
                                             const float* E, float* vw, float* cx,
                                             float* xF, float* rLam, float* cpack,
                                             float* invSt) {
  const int bid = blockIdx.x;
  const int t = threadIdx.x;
  if (bid < 128) {
    dev_T(u, vw, bid, t);  // all 512 threads participate (internal barriers)
  } else if (bid == 128) {
    if (t < 256) dev_prep(x, C1, Fm, Lam, cx, xF, rLam, t);  // no barriers inside
  } else if (bid == 129) {
    if (t < 256) dev_pack(D11, cpack, t);  // no barriers inside
  } else {
    dev_inv(E, 256, invSt, t, 0, 4);  // bid == 130: inv1 first half
  }
}

__global__ __launch_bounds__(512) void mega2(const float* D12, const float* cx,
                                             float* vw, const float* invSt,
                                             float* inv1T) {
  const int bid = blockIdx.x;
  const int t = threadIdx.x;
  if (bid < 128) dev_du512(D12, cx, vw, bid, t);
  else dev_inv(invSt, 128, inv1T, t, 4, 8);  // bid == 128: inv1 second half
}

__global__ __launch_bounds__(512) void mega3(const float* cpack, const float* rLam,
                                             float* vw, const float* E,
                                             const float* C2, const float* inv1T,
                                             float* W, float* z1) {
  const int bid = blockIdx.x;
  const int t = threadIdx.x;
  if (bid < 32) {
    dev_scan(cpack, rLam, vw, 0, bid, t);  // all 512 stage; t<256 run recurrence
  } else {
    dev_WZ(E, C2, inv1T, W, z1, (bid - 32) * 512 + t);  // 64 blocks
  }
}

__global__ __launch_bounds__(512) void mega4(const float* D11, float* vw,
                                             const float* E, const float* C2,
                                             const float* W, const float* z1,
                                             float* STt, float* c2p) {
  const int bid = blockIdx.x;
  const int t = threadIdx.x;
  if (bid < 96) dev_upd(D11, vw, 0, bid * 2 + (t >> 8), t & 255);  // roles 0..191
  else dev_SC(E, C2, W, z1, STt, c2p, (bid - 96) * 512 + t);       // 64 blocks
}

__global__ __launch_bounds__(512) void mega5(const float* cpack, const float* rLam,
                                             float* vw, const float* STt,
                                             float* inv2St) {
  const int bid = blockIdx.x;
  const int t = threadIdx.x;
  if (bid < 32) {
    dev_scan(cpack, rLam, vw, 1, bid, t);
  } else {
    dev_inv(STt, 128, inv2St, t, 0, 4);  // bid == 32: inv2 first half
  }
}

__global__ __launch_bounds__(512) void mega6(const float* D11, float* vw,
                                             const float* inv2St, float* inv2T) {
  const int bid = blockIdx.x;
  const int t = threadIdx.x;
  if (bid < 64) dev_upd(D11, vw, 1, bid * 2 + (t >> 8), t & 255);  // roles 0..127
  else dev_inv(inv2St, 128, inv2T, t, 4, 8);  // bid == 64: inv2 second half
}

__global__ __launch_bounds__(512) void mega7(const float* cpack, const float* rLam,
                                             float* vw, const float* inv2T,
                                             const float* c2p, float* g2) {
  const int bid = blockIdx.x;
  const int t = threadIdx.x;
  if (bid < 32) {
    dev_scan(cpack, rLam, vw, 2, bid, t);
  } else {
    dev_G2(inv2T, c2p, g2, (bid - 32) * 512 + t);  // 32 blocks
  }
}

__global__ __launch_bounds__(512) void mega8(const float* D11, float* vw,
                                             const float* W, const float* z1,
                                             const float* g2, float* g1) {
  const int bid = blockIdx.x;
  const int t = threadIdx.x;
  if (bid < 32) dev_upd(D11, vw, 2, bid * 2 + (t >> 8), t & 255);  // roles 0..63
  else dev_G1(W, z1, g2, g1, (bid - 32) * 512 + t);  // 32 blocks
}

__global__ __launch_bounds__(512) void mega9(const float* cpack, const float* rLam,
                                             float* vw, const float* B1,
                                             const float* B2, const float* D21,
                                             const float* D22, const float* g1,
                                             const float* g2, const float* xF,
                                             float* R, float* y0) {
  const int bid = blockIdx.x;
  const int t = threadIdx.x;
  if (bid < 32) {
    dev_scan(cpack, rLam, vw, 3, bid, t);
  } else {
    dev_R(B1, B2, D21, D22, g1, g2, xF, R, y0, (bid - 32) * 512 + t);  // 97 blk
  }
}

// ---------- y[b][o] = y0[o] + sum_{k<384} R[o][k] vw[k][b] ----------
// v4 MEASURED (R17): wall 334->321, k_y out of top-5 (<42us). o-tile 4 halves
// L3 reads; in-block k-split (ks=t>>8) + LDS combine; zero atomics (R12: global
// atomics on y resolve at HBM, WRITE 4->64MB -- never again).
__global__ __launch_bounds__(512) void k_y(const float* __restrict__ vw,
                                           const float* __restrict__ R,
                                           const float* __restrict__ y0,
                                           float* __restrict__ y) {
  __shared__ float Rl[1536];        // [j][k] 4 x 384
  __shared__ float part[256 * 16];  // ks=1 partials: [lane][bi*4+j]
  const int tid = threadIdx.x;      // 0..511
  const int bid = blockIdx.x;       // 256 blocks
  const int gx = bid & 7;           // b-tile (XCD-aligned)
  const int gy = bid >> 3;          // o-tile, 0..31
  const int o0 = gy * 4;
#pragma unroll
  for (int q = 0; q < 3; ++q) Rl[q * 512 + tid] = R[o0 * 384 + q * 512 + tid];
  __syncthreads();

  const int lane = tid & 255;
  const int ks = tid >> 8;  // k-half, 0..1
  const int kbase = ks * 192;
  const float4* vw4 = (const float4*)vw;
  const int b4 = gx * 256 + lane;
  float acc[4][4];
#pragma unroll
  for (int j = 0; j < 4; ++j)
#pragma unroll
    for (int bi = 0; bi < 4; ++bi) acc[bi][j] = 0.f;

  for (int k = 0; k < 192; k += 8) {
    float4 w[8];
#pragma unroll
    for (int kk = 0; kk < 8; ++kk) w[kk] = vw4[(kbase + k + kk) * 2048 + b4];
#pragma unroll
    for (int j = 0; j < 4; ++j) {
      const float4 r0 = *(const float4*)&Rl[j * 384 + kbase + k];
      const float4 r1 = *(const float4*)&Rl[j * 384 + kbase + k + 4];
      acc[0][j] += r0.x * w[0].x + r0.y * w[1].x + r0.z * w[2].x + r0.w * w[3].x +
                   r1.x * w[4].x + r1.y * w[5].x + r1.z * w[6].x + r1.w * w[7].x;
      acc[1][j] += r0.x * w[0].y + r0.y * w[1].y + r0.z * w[2].y + r0.w * w[3].y +
                   r1.x * w[4].y + r1.y * w[5].y + r1.z * w[6].y + r1.w * w[7].y;
      acc[2][j] += r0.x * w[0].z + r0.y * w[1].z + r0.z * w[2].z + r0.w * w[3].z +
                   r1.x * w[4].z + r1.y * w[5].z + r1.z * w[6].z + r1.w * w[7].z;
      acc[3][j] += r0.x * w[0].w + r0.y * w[1].w + r0.z * w[2].w + r0.w * w[3].w +
                   r1.x * w[4].w + r1.y * w[5].w + r1.z * w[6].w + r1.w * w[7].w;
    }
  }

  if (ks == 1) {
#pragma unroll
    for (int bi = 0; bi < 4; ++bi)
      *(float4*)&part[lane * 16 + bi * 4] =
          make_float4(acc[bi][0], acc[bi][1], acc[bi][2], acc[bi][3]);
  }
  __syncthreads();
  if (ks == 0) {
    const int b0 = b4 * 4;
#pragma unroll
    for (int bi = 0; bi < 4; ++bi) {
      const float4 p = *(const float4*)&part[lane * 16 + bi * 4];
      *(float4*)&y[(b0 + bi) * 128 + o0] =
          make_float4(acc[bi][0] + p.x + y0[o0 + 0],
                      acc[bi][1] + p.y + y0[o0 + 1],
                      acc[bi][2] + p.z + y0[o0 + 2],
                      acc[bi][3] + p.w + y0[o0 + 3]);
    }
  }
}

extern "C" void kernel_launch(void* const* d_in, const int* in_sizes, int n_in,
                              void* d_out, int out_size, void* d_ws, size_t ws_size,
                              hipStream_t stream) {
  const float* u   = (const float*)d_in[0];   // (8192,1,128)
  const float* x   = (const float*)d_in[1];   // (1,1,256)
  const float* Fm  = (const float*)d_in[2];   // (256,256)
  const float* B1  = (const float*)d_in[3];   // (256,256)
  const float* B2  = (const float*)d_in[4];   // (256,128)
  const float* C1  = (const float*)d_in[5];   // (256,256)
  const float* C2  = (const float*)d_in[6];   // (128,256)
  const float* D11 = (const float*)d_in[7];   // (256,256) strictly lower
  const float* D12 = (const float*)d_in[8];   // (256,128)
  const float* D21 = (const float*)d_in[9];   // (128,256)
  const float* D22 = (const float*)d_in[10];  // (128,128)
  const float* E   = (const float*)d_in[11];  // (256,256)
  const float* Lam = (const float*)d_in[12];  // (256,)
  float* y = (float*)d_out;                   // (8192,1,128) fp32

  float* F = (float*)d_ws;                     // ~13.4 MB used
  float* vw    = F;                            // 384*8192 (rows 256..383 = u^T)
  float* SMb   = F + 384 * NB;
  float* inv1T = SMb;                          // 16384
  float* Wm    = SMb + 16384;
  float* z1    = SMb + 32768;
  float* STt   = SMb + 49152;
  float* c2p   = SMb + 65536;
  float* inv2T = SMb + 81920;
  float* g2    = SMb + 98304;
  float* g1    = SMb + 114688;
  float* Rm    = SMb + 131072;                 // 128*384
  float* y0v   = SMb + 180224;                 // 128
  float* cx    = SMb + 180352;                 // 256
  float* xF    = SMb + 180608;                 // 256
  float* rLam  = SMb + 180864;                 // 256
  float* cpack = SMb + 181120;                 // 4*2176
  // inverse mid-state spills ALIAS dead regions (footprint unchanged):
  // invSt (inv1 state, live k1->k2) reuses STt (first written in k4);
  // inv2St (inv2 state, live k5->k6) reuses g1 (first written in k8).
  float* invSt  = STt;
  float* inv2St = g1;

  mega1<<<131, 512, 0, stream>>>(u, x, C1, Fm, Lam, D11, E, vw, cx, xF, rLam,
                                 cpack, invSt);
  mega2<<<129, 512, 0, stream>>>(D12, cx, vw, invSt, inv1T);
  mega3<<<96, 512, 0, stream>>>(cpack, rLam, vw, E, C2, inv1T, Wm, z1);
  mega4<<<160, 512, 0, stream>>>(D11, vw, E, C2, Wm, z1, STt, c2p);
  mega5<<<33, 512, 0, stream>>>(cpack, rLam, vw, STt, inv2St);
  mega6<<<65, 512, 0, stream>>>(D11, vw, inv2St, inv2T);
  mega7<<<64, 512, 0, stream>>>(cpack, rLam, vw, inv2T, c2p, g2);
  mega8<<<64, 512, 0, stream>>>(D11, vw, Wm, z1, g2, g1);
  mega9<<<129, 512, 0, stream>>>(cpack, rLam, vw, B1, B2, D21, D22, g1, g2, xF,
                                 Rm, y0v);
  k_y<<<256, 512, 0, stream>>>(vw, Rm, y0v, y);
}